// Round 2
// baseline (264.250 us; speedup 1.0000x reference)
//
#include <hip/hip_runtime.h>

#define SIG 2.8853900817779268f           // 2 * log2(e)
#define INV_SIG4 0.01442968963485602f     // 1 / SIG^4

__device__ __forceinline__ float rcp_f (float x){ return __builtin_amdgcn_rcpf(x);  }
__device__ __forceinline__ float exp2_f(float x){ return __builtin_amdgcn_exp2f(x); }

// Block: 448 threads = 7 waves; wave s handles permutation s for 64 consecutive m.
// 1024 blocks = 4 blocks/CU exactly; (448,7) keeps VGPR cap at 512/7=73 for that.
__global__ __launch_bounds__(448, 7) void maron_kernel(
    const float* __restrict__ x,      // (64,14,1024)
    const float* __restrict__ W1,     // (14,16)
    const float* __restrict__ b1,     // (16)
    const float* __restrict__ W2,     // (16,1)
    const float* __restrict__ b2p,    // (1)
    const float* __restrict__ fW1,    // (120,16)
    const float* __restrict__ fb1,    // (16)
    const float* __restrict__ fW2,    // (16,1)
    const float* __restrict__ fb2p,   // (1)
    float* __restrict__ out,          // (M) out ++ (M) L
    int M)
{
    __shared__ float red[7][64][17];  // stride 17 (odd) -> conflict-free

    const int tid = threadIdx.x;
    const int s   = tid >> 6;         // 0..6  (wave-uniform)
    const int ml  = tid & 63;
    const int m   = blockIdx.x * 64 + ml;
    const int bb  = m >> 10;
    const int tt  = m & 1023;

    const float* xb = x + (size_t)bb * 14 * 1024 + tt;

    const int i0 = (7 - s) % 7;
    const int i1 = (8 - s) % 7;

    const float u = xb[(i0    ) * 1024];
    const float v = xb[(i1    ) * 1024];
    const float w = xb[(7 + i0) * 1024];
    float       z = xb[(7 + i1) * 1024];
    // clamp so z^7 stays a normal float and the rcp-descend chain is exact at d=0.
    z = fmaxf(z, 3.814697265625e-6f);           // 2^-18
    const float rz = rcp_f(z);

    // Bias incl. the 10 always-one slots, pre-scaled by SIG for the tanh-exp trick
    float Bs[16];
#pragma unroll
    for (int k = 0; k < 16; ++k) {
        float t = b1[k];
        t += W1[2*16+k] + W1[3*16+k] + W1[4*16+k] + W1[5*16+k] + W1[6*16+k];
        t += W1[9*16+k] + W1[10*16+k] + W1[11*16+k] + W1[12*16+k] + W1[13*16+k];
        Bs[k] = SIG * t;
    }
    float C2 = b2p[0];
#pragma unroll
    for (int k = 0; k < 16; ++k) C2 += W2[k];

    float acc[16];
#pragma unroll
    for (int k = 0; k < 16; ++k) acc[k] = 0.f;
    float Lsum = 0.f;

    // SIG * z^7 (start of the descending d-chain)
    const float z2 = z * z, z4 = z2 * z2;
    float zna = SIG * (z4 * z2 * z);   // SIG * z^(7-a), a=0
    float spa = SIG;                   // SIG * u^a

    int r = 0;
    for (int a = 0; a <= 7; ++a) {
        float A_[16];
#pragma unroll
        for (int k = 0; k < 16; ++k) A_[k] = fmaf(spa, W1[0*16+k], Bs[k]);

        float spb = SIG;               // SIG * v^b
        float znb = zna;               // SIG * z^(7-a-b)
        const float paS = spa * INV_SIG4;

        for (int bi = 0; bi <= 7 - a; ++bi) {
            float AB_[16];
#pragma unroll
            for (int k = 0; k < 16; ++k) AB_[k] = fmaf(spb, W1[1*16+k], A_[k]);

            const float pab2 = paS * spb;     // u^a v^b / SIG^2
            float spc = SIG;                  // SIG * w^c
            float spd = znb;                  // SIG * z^d, d = 7-a-b-c
            const int cmax = 7 - a - bi;

            for (int ci = 0; ci <= cmax; ++ci, ++r) {
                // prefetch the (wave-uniform) feat_W1 row so the s_load hides
                // under the 16 sigmoids
                const float* frow = fW1 + (r << 4);
                float fr[16];
#pragma unroll
                for (int k = 0; k < 16; ++k) fr[k] = frow[k];

                float s2 = 0.f;
#pragma unroll
                for (int k = 0; k < 16; ++k) {
                    const float tk = fmaf(spd, W1[8*16+k], fmaf(spc, W1[7*16+k], AB_[k]));
                    const float rk = rcp_f(exp2_f(tk) + 1.0f);
                    s2 = fmaf(W2[k], rk, s2);
                }
                const float mulnn = fmaf(-2.f, s2, C2);      // b2 + sum W2*tanh
                const float mulT  = pab2 * (spc * spd);      // u^a v^b w^c z^d
                Lsum += fabsf(mulT - mulnn);

#pragma unroll
                for (int k = 0; k < 16; ++k) acc[k] = fmaf(mulnn, fr[k], acc[k]);

                spc *= w;      // c -> c+1
                spd *= rz;     // d -> d-1
            }
            spb *= v;          // b -> b+1
            znb *= rz;
        }
        spa *= u;              // a -> a+1
        zna *= rz;
    }

    // reduce the 7 permutations
#pragma unroll
    for (int k = 0; k < 16; ++k) red[s][ml][k] = acc[k];
    red[s][ml][16] = Lsum;
    __syncthreads();

    if (tid < 64) {
        float aq[16];
#pragma unroll
        for (int k = 0; k < 16; ++k) aq[k] = red[0][ml][k];
        float Lt = red[0][ml][16];
#pragma unroll
        for (int ss = 1; ss < 7; ++ss) {
#pragma unroll
            for (int k = 0; k < 16; ++k) aq[k] += red[ss][ml][k];
            Lt += red[ss][ml][16];
        }

        float o = fb2p[0];
        float s3 = 0.f;
#pragma unroll
        for (int k = 0; k < 16; ++k) {
            const float a2 = SIG * (aq[k] + fb1[k]);
            const float rk = rcp_f(exp2_f(a2) + 1.f);
            s3 = fmaf(fW2[k], rk, s3);
            o += fW2[k];
        }
        o = fmaf(-2.f, s3, o);

        out[m]     = o;
        out[M + m] = Lt * (1.f / 120.f);
    }
}

extern "C" void kernel_launch(void* const* d_in, const int* in_sizes, int n_in,
                              void* d_out, int out_size, void* d_ws, size_t ws_size,
                              hipStream_t stream) {
    const float* x   = (const float*)d_in[0];
    const float* W1  = (const float*)d_in[1];
    const float* b1  = (const float*)d_in[2];
    const float* W2  = (const float*)d_in[3];
    const float* b2  = (const float*)d_in[4];
    const float* fW1 = (const float*)d_in[5];
    const float* fb1 = (const float*)d_in[6];
    const float* fW2 = (const float*)d_in[7];
    const float* fb2 = (const float*)d_in[8];

    const int M = out_size / 2;           // 65536
    const int blocks = M / 64;            // 1024

    maron_kernel<<<blocks, 448, 0, stream>>>(x, W1, b1, W2, b2, fW1, fb1, fW2, fb2,
                                             (float*)d_out, M);
}

// Round 3
// 253.902 us; speedup vs baseline: 1.0408x; 1.0408x over previous
//
#include <hip/hip_runtime.h>

#define SIG 2.8853900817779268f           // 2 * log2(e)
#define INV_SIG4 0.01442968963485602f     // 1 / SIG^4

__device__ __forceinline__ float rcp_f (float x){ return __builtin_amdgcn_rcpf(x);  }
__device__ __forceinline__ float exp2_f(float x){ return __builtin_amdgcn_exp2f(x); }

// Block: 448 threads = 7 waves; wave s handles permutation s for 64 consecutive m.
__global__ __launch_bounds__(448) void maron_kernel(
    const float* __restrict__ x,      // (64,14,1024)
    const float* __restrict__ W1,     // (14,16)
    const float* __restrict__ b1,     // (16)
    const float* __restrict__ W2,     // (16,1)
    const float* __restrict__ b2p,    // (1)
    const float* __restrict__ fW1,    // (120,16)
    const float* __restrict__ fb1,    // (16)
    const float* __restrict__ fW2,    // (16,1)
    const float* __restrict__ fb2p,   // (1)
    float* __restrict__ out,          // (M) out ++ (M) L
    int M)
{
    __shared__ float red[7][64][17];  // stride 17 (odd) -> conflict-free

    const int tid = threadIdx.x;
    const int s   = tid >> 6;         // 0..6  (wave-uniform)
    const int ml  = tid & 63;
    const int m   = blockIdx.x * 64 + ml;
    const int bb  = m >> 10;
    const int tt  = m & 1023;

    const float* xb = x + (size_t)bb * 14 * 1024 + tt;

    const int i0 = (7 - s) % 7;
    const int i1 = (8 - s) % 7;

    const float u = xb[(i0    ) * 1024];
    const float v = xb[(i1    ) * 1024];
    const float w = xb[(7 + i0) * 1024];
    float       z = xb[(7 + i1) * 1024];
    // clamp so z^7 stays normal and the rcp-descend chain is exact at d=0
    z = fmaxf(z, 3.814697265625e-6f);           // 2^-18
    const float rz = rcp_f(z);

    // ---- wave-uniform precompute (compiler scalarizes) ----
    // Bias incl. the 10 always-one slots, pre-scaled by SIG (tanh-exp trick);
    // cap[k]: AB clamp so tk <= 24 always (pure inf-guard for the quad merge,
    // never active for realistic pre-activations).
    float Bs[16], cap[16], Wt[16];
#pragma unroll
    for (int k = 0; k < 16; ++k) {
        float t = b1[k];
        t += W1[2*16+k] + W1[3*16+k] + W1[4*16+k] + W1[5*16+k] + W1[6*16+k];
        t += W1[9*16+k] + W1[10*16+k] + W1[11*16+k] + W1[12*16+k] + W1[13*16+k];
        Bs[k]  = SIG * t;
        cap[k] = 24.f - SIG * (fabsf(W1[7*16+k]) + fabsf(W1[8*16+k]));
        Wt[k]  = -2.f * W2[k];
    }
    float C2 = b2p[0];
#pragma unroll
    for (int k = 0; k < 16; ++k) C2 += W2[k];
    float Sp[8];
#pragma unroll
    for (int p = 0; p < 8; ++p) Sp[p] = Wt[2*p] + Wt[2*p+1];

    float acc[16];
#pragma unroll
    for (int k = 0; k < 16; ++k) acc[k] = 0.f;
    float Lsum = 0.f;

    // SIG * z^7 (start of the descending d-chain)
    const float z2 = z * z, z4 = z2 * z2;
    float zna = SIG * (z4 * z2 * z);   // SIG * z^(7-a), a=0
    float spa = SIG;                   // SIG * u^a

    int r = 0;
    for (int a = 0; a <= 7; ++a) {
        float A_[16];
#pragma unroll
        for (int k = 0; k < 16; ++k) A_[k] = fmaf(spa, W1[0*16+k], Bs[k]);

        float spb = SIG;               // SIG * v^b
        float znb = zna;               // SIG * z^(7-a-b)
        const float paS = spa * INV_SIG4;

        for (int bi = 0; bi <= 7 - a; ++bi) {
            float AB_[16];
#pragma unroll
            for (int k = 0; k < 16; ++k)
                AB_[k] = fminf(fmaf(spb, W1[1*16+k], A_[k]), cap[k]);

            const float pab2 = paS * spb;     // u^a v^b / SIG^2
            float spc = SIG;                  // SIG * w^c
            float spd = znb;                  // SIG * z^d, d = 7-a-b-c
            const int cmax = 7 - a - bi;

            for (int ci = 0; ci <= cmax; ++ci, ++r) {
                const float* frow = fW1 + (r << 4);   // wave-uniform row

                // mulnn = C2 + sum_k Wt[k]/(1+2^tk), merged 4 sigmoids -> 1 rcp
                float s2 = C2;
#pragma unroll
                for (int qd = 0; qd < 4; ++qd) {
                    const int k0 = qd * 4;
                    const float t0 = fmaf(spd, W1[8*16+k0+0], fmaf(spc, W1[7*16+k0+0], AB_[k0+0]));
                    const float t1 = fmaf(spd, W1[8*16+k0+1], fmaf(spc, W1[7*16+k0+1], AB_[k0+1]));
                    const float t2 = fmaf(spd, W1[8*16+k0+2], fmaf(spc, W1[7*16+k0+2], AB_[k0+2]));
                    const float t3 = fmaf(spd, W1[8*16+k0+3], fmaf(spc, W1[7*16+k0+3], AB_[k0+3]));
                    const float E0 = exp2_f(t0);
                    const float E1 = exp2_f(t1);
                    const float E2 = exp2_f(t2);
                    const float E3 = exp2_f(t3);
                    // pair merges: N over common denom (1+Ei)(1+Ej) = 1+dij
                    const float n01 = fmaf(Wt[k0+1], E0, fmaf(Wt[k0+0], E1, Sp[2*qd+0]));
                    const float d01 = fmaf(E0, E1, E0 + E1);
                    const float n23 = fmaf(Wt[k0+3], E2, fmaf(Wt[k0+2], E3, Sp[2*qd+1]));
                    const float d23 = fmaf(E2, E3, E2 + E3);
                    // quad merge
                    const float Nq = fmaf(n01, d23, fmaf(n23, d01, n01 + n23));
                    const float dq = fmaf(d01, d23, d01 + d23);
                    s2 = fmaf(Nq, rcp_f(dq + 1.f), s2);
                }
                const float mulnn = s2;
                const float mulT  = pab2 * (spc * spd);      // u^a v^b w^c z^d
                Lsum += fabsf(mulT - mulnn);

#pragma unroll
                for (int k = 0; k < 16; ++k) acc[k] = fmaf(mulnn, frow[k], acc[k]);

                spc *= w;      // c -> c+1
                spd *= rz;     // d -> d-1
            }
            spb *= v;          // b -> b+1
            znb *= rz;
        }
        spa *= u;              // a -> a+1
        zna *= rz;
    }

    // reduce the 7 permutations
#pragma unroll
    for (int k = 0; k < 16; ++k) red[s][ml][k] = acc[k];
    red[s][ml][16] = Lsum;
    __syncthreads();

    if (tid < 64) {
        float aq[16];
#pragma unroll
        for (int k = 0; k < 16; ++k) aq[k] = red[0][ml][k];
        float Lt = red[0][ml][16];
#pragma unroll
        for (int ss = 1; ss < 7; ++ss) {
#pragma unroll
            for (int k = 0; k < 16; ++k) aq[k] += red[ss][ml][k];
            Lt += red[ss][ml][16];
        }

        float o = fb2p[0];
        float s3 = 0.f;
#pragma unroll
        for (int k = 0; k < 16; ++k) {
            const float a2 = SIG * (aq[k] + fb1[k]);
            const float rk = rcp_f(exp2_f(a2) + 1.f);
            s3 = fmaf(fW2[k], rk, s3);
            o += fW2[k];
        }
        o = fmaf(-2.f, s3, o);

        out[m]     = o;
        out[M + m] = Lt * (1.f / 120.f);
    }
}

extern "C" void kernel_launch(void* const* d_in, const int* in_sizes, int n_in,
                              void* d_out, int out_size, void* d_ws, size_t ws_size,
                              hipStream_t stream) {
    const float* x   = (const float*)d_in[0];
    const float* W1  = (const float*)d_in[1];
    const float* b1  = (const float*)d_in[2];
    const float* W2  = (const float*)d_in[3];
    const float* b2  = (const float*)d_in[4];
    const float* fW1 = (const float*)d_in[5];
    const float* fb1 = (const float*)d_in[6];
    const float* fW2 = (const float*)d_in[7];
    const float* fb2 = (const float*)d_in[8];

    const int M = out_size / 2;           // 65536
    const int blocks = M / 64;            // 1024

    maron_kernel<<<blocks, 448, 0, stream>>>(x, W1, b1, W2, b2, fW1, fb1, fW2, fb2,
                                             (float*)d_out, M);
}